// Round 5
// baseline (70.151 us; speedup 1.0000x reference)
//
#include <hip/hip_runtime.h>
#include <hip/hip_fp16.h>

#define CUT_SIZE 224
#define SIDE 1024
#define CUTN 128
#define LDSW2 1032   // halves per channel row (max index needed 1027) + slack

// One wave per output row, all 3 channels batched:
//   stage: ONE loop issues 6 independent float4 loads/iter (3ch x rows y0,y1),
//          y-lerps in registers, packs to fp16, writes 3 LDS rows (8B ds_write).
//   ONE lgkmcnt(0) wait, then gather all 3 channels (2x ds_read_u16/pixel).
// fp16 rows: 6.2 KB/wave -> 24.8 KB per 4-wave block -> 6 blocks/CU (24 waves).
// No __syncthreads (LDS rows are wave-private). XCD-chunked block swizzle.
__global__ __launch_bounds__(256) void make_cutouts_kernel(
    const float* __restrict__ img,     // [3, 1024, 1024]
    const int* __restrict__ sizes,     // [128]
    const int* __restrict__ offy,      // [128]
    const int* __restrict__ offx,      // [128]
    float* __restrict__ out)           // [128, 3, 224, 224]
{
    __shared__ __half lds[4][3][LDSW2];

    // XCD-chunked swizzle: 7168 blocks, XCD = bid%8 (round-robin heuristic).
    // Each XCD gets 16 whole cutouts -> per-cutout L2 locality + balance.
    const int bid = blockIdx.x;
    const int n   = (bid & 7) * 16 + ((bid >> 3) / 56);   // cutout 0..127
    const int rg  = (bid >> 3) % 56;                      // row group 0..55
    const int w    = threadIdx.x >> 6;                    // wave 0..3
    const int lane = threadIdx.x & 63;
    const int y    = rg * 4 + w;                          // output row 0..223

    const float scale = (float)sizes[n] * (1.0f / (float)CUT_SIZE);
    const float oy = (float)offy[n];
    const float ox = (float)offx[n];

    // y coordinate (align_corners=False), clipped
    float fy = fmaf((float)y + 0.5f, scale, oy - 0.5f);
    fy = fminf(fmaxf(fy, 0.0f), (float)(SIDE - 1));
    const int   y0 = (int)fy;
    const int   y1 = min(y0 + 1, SIDE - 1);
    const float wy  = fy - (float)y0;
    const float wy0 = 1.0f - wy;

    // x span (wave-uniform for cutout n)
    float fx0 = fmaf(0.5f, scale, ox - 0.5f);
    fx0 = fminf(fmaxf(fx0, 0.0f), (float)(SIDE - 1));
    float fxl = fmaf((float)CUT_SIZE - 0.5f, scale, ox - 0.5f);
    fxl = fminf(fmaxf(fxl, 0.0f), (float)(SIDE - 1));
    const int xb    = (int)fx0;
    const int xe    = min((int)fxl + 1, SIDE - 1);  // inclusive last needed col
    const int xb4   = xb & ~3;                      // 16B-aligned load base
    const int ilast = xe - xb4;                     // last valid row index
    const int nf4   = (ilast >> 2) + 1;             // float4 count (wave-uniform)
    // Last load base = xb4+4*(nf4-1) <= xe and 4-aligned => <= 1020: never OOB.

    // Precompute x-mapping once (shared by all 3 channels).
    int   i0r[4];
    float wxr[4], wx0r[4];
#pragma unroll
    for (int it = 0; it < 4; ++it) {
        const int p = min(lane + it * 64, CUT_SIZE - 1);   // stores guarded below
        float fx = fmaf((float)p + 0.5f, scale, ox - 0.5f);
        fx = fminf(fmaxf(fx, 0.0f), (float)(SIDE - 1));
        const float fl = fx - (float)xb4;                  // >= 0
        const int   i0 = (int)fl;
        i0r[it]  = i0;                                     // i1 = i0+1 always (pad below)
        wxr[it]  = fl - (float)i0;
        wx0r[it] = 1.0f - wxr[it];
    }

    const size_t cstride = (size_t)SIDE * SIDE;
    const float* base0 = img + (size_t)y0 * SIDE + xb4;
    const float* base1 = img + (size_t)y1 * SIDE + xb4;
    const float4* __restrict__ rp[6] = {
        reinterpret_cast<const float4*>(base0),
        reinterpret_cast<const float4*>(base1),
        reinterpret_cast<const float4*>(base0 + cstride),
        reinterpret_cast<const float4*>(base1 + cstride),
        reinterpret_cast<const float4*>(base0 + 2 * cstride),
        reinterpret_cast<const float4*>(base1 + 2 * cstride),
    };
    __half* __restrict__ l0 = &lds[w][0][0];
    __half* __restrict__ l1 = &lds[w][1][0];
    __half* __restrict__ l2 = &lds[w][2][0];

    // Stage all 3 channels: 6 independent float4 loads per iteration.
    for (int i = lane; i < nf4; i += 64) {
        const float4 a0 = rp[0][i], b0 = rp[1][i];
        const float4 a1 = rp[2][i], b1 = rp[3][i];
        const float4 a2 = rp[4][i], b2 = rp[5][i];
        union { __half2 h[2]; uint2 u; } pk;
        pk.h[0] = __floats2half2_rn(a0.x * wy0 + b0.x * wy, a0.y * wy0 + b0.y * wy);
        pk.h[1] = __floats2half2_rn(a0.z * wy0 + b0.z * wy, a0.w * wy0 + b0.w * wy);
        *reinterpret_cast<uint2*>(l0 + 4 * i) = pk.u;
        pk.h[0] = __floats2half2_rn(a1.x * wy0 + b1.x * wy, a1.y * wy0 + b1.y * wy);
        pk.h[1] = __floats2half2_rn(a1.z * wy0 + b1.z * wy, a1.w * wy0 + b1.w * wy);
        *reinterpret_cast<uint2*>(l1 + 4 * i) = pk.u;
        pk.h[0] = __floats2half2_rn(a2.x * wy0 + b2.x * wy, a2.y * wy0 + b2.y * wy);
        pk.h[1] = __floats2half2_rn(a2.z * wy0 + b2.z * wy, a2.w * wy0 + b2.w * wy);
        *reinterpret_cast<uint2*>(l2 + 4 * i) = pk.u;
    }
    // Pad: zero at ilast+1 per row so i1=i0+1 is always readable (the only case
    // hitting it has wx==0, so 0*0 contributes nothing; avoids stale-LDS NaNs).
    if (lane < 3) lds[w][lane][ilast + 1] = __float2half(0.0f);
    // Wave-private LDS: drain this wave's DS writes; "memory" stops reordering.
    asm volatile("s_waitcnt lgkmcnt(0)" ::: "memory");

    const size_t obase0 = (((size_t)n * 3) * CUT_SIZE + y) * CUT_SIZE;
#pragma unroll
    for (int c = 0; c < 3; ++c) {
        const __half* __restrict__ lc = &lds[w][c][0];
        const size_t obase = obase0 + (size_t)c * (CUT_SIZE * CUT_SIZE);
#pragma unroll
        for (int it = 0; it < 4; ++it) {
            const int p = lane + it * 64;
            if (p < CUT_SIZE) {
                const int i0 = i0r[it];
                const float v0 = __half2float(lc[i0]);
                const float v1 = __half2float(lc[i0 + 1]);
                float v = v0 * wx0r[it] + v1 * wxr[it];
                v = fminf(fmaxf(v, 0.0f), 1.0f);
                out[obase + p] = v;
            }
        }
    }
}

extern "C" void kernel_launch(void* const* d_in, const int* in_sizes, int n_in,
                              void* d_out, int out_size, void* d_ws, size_t ws_size,
                              hipStream_t stream) {
    const float* img   = (const float*)d_in[0];
    const int*   sizes = (const int*)d_in[1];
    const int*   offy  = (const int*)d_in[2];
    const int*   offx  = (const int*)d_in[3];
    float*       out   = (float*)d_out;

    dim3 grid(CUTN * (CUT_SIZE / 4), 1, 1);   // 128 cutouts x 56 row-groups = 7168
    dim3 block(256, 1, 1);
    make_cutouts_kernel<<<grid, block, 0, stream>>>(img, sizes, offy, offx, out);
}